// Round 4
// baseline (460.458 us; speedup 1.0000x reference)
//
#include <hip/hip_runtime.h>
#include <stdint.h>

#define N_IDS     1000000
#define ZCH       400000
#define EMB_DIM   128
#define TOTAL     (2 * N_IDS)
#define HASH_SZ   4000000            // id values are in [0, 4M)
#define BLOCK     256
#define GRID      ((TOTAL + BLOCK - 1) / BLOCK)   // 7813
#define OVF       (ZCH - 1)

// Round-4 structure: NO LUT, NO build kernel. Each thread does the
// reference's searchsorted-left directly against mch (sorted int32).
// Both mch tables = 3.2 MB total < one XCD's 4 MB L2 -> top ~7 search
// levels are L1-broadcast, rest L2-resident. Latency hides under 31 K
// waves of TLP. This removes: build kernel (500 K searches + 8 MB
// write), the 8 MB cold LUT re-fetch in remap, one dependent launch gap.
// Pipeline = 2 dispatches: remap_loss -> finalize.
//
// R2 lesson kept: no per-block __threadfence fusion (device-scope fences
// per block = per-XCD L2 writeback storm, +370 us). Separate finalize.
//
// d_out (float32): [0] = loss, [1 .. 2M] = remapped indices as floats.
// d_ws: [partials: GRID floats] only (~31 KB).

__global__ __launch_bounds__(BLOCK) void remap_loss_kernel(
    const int* __restrict__ ids0, const int* __restrict__ ids1,
    const int* __restrict__ mch0, const int* __restrict__ mch1,
    const float* __restrict__ emb0, const float* __restrict__ emb1,
    float* __restrict__ out,
    float* __restrict__ partials)
{
    const int gid  = blockIdx.x * BLOCK + threadIdx.x;
    const int lane = threadIdx.x & 63;
    const int wave = threadIdx.x >> 6;

    float accl = 0.0f;

    // Wave-uniform activity/feature: TOTAL % 64 == 0 and N_IDS % 64 == 0.
    const bool active = (gid < TOTAL);
    if (active) {
        const int feat = gid >= N_IDS;
        const int i    = feat ? (gid - N_IDS) : gid;
        const int id   = (feat ? ids1 : ids0)[i];
        const int* __restrict__ mch = feat ? mch1 : mch0;
        const float* __restrict__ emb = feat ? emb1 : emb0;

        // searchsorted-left (reference semantics), then clip + hit-check.
        // 19 levels; levels 0-6 touch the same lines for all threads (L1),
        // the rest stay L2-resident (whole table is 1.6 MB/feature).
        int lo = 0, hi = ZCH;
        while (lo < hi) {
            const int mid = (lo + hi) >> 1;
            if (mch[mid] < id) lo = mid + 1; else hi = mid;
        }
        // pos = clip(lo, 0, ZCH-1); rem = (mch[pos]==id) ? pos : OVF
        const int rem = (lo < ZCH && mch[lo] == id) ? lo : OVF;

        out[1 + gid] = (float)rem;                  // exact: rem < 2^24

        // ---- loss ----
        // ~90.5% of ids hit the overflow row: dedupe it (L1-hot).
        const unsigned long long ovf = __ballot(rem == OVF);
        const int novf = __popcll(ovf);
        if (novf) {
            const float2* __restrict__ row =
                (const float2*)(emb + (size_t)OVF * EMB_DIM);
            float2 v = row[lane];                   // 64 x 8 B = one row
            float s = v.x + v.y;
            #pragma unroll
            for (int o = 32; o > 0; o >>= 1)
                s += __shfl_xor(s, o, 64);
            if (lane == 0) accl += (float)novf * s;
        }

        // Remaining ~6 distinct rows per wave: 2 rows/iteration,
        // half-wave x float4 (32 x 16 B = 512 B = one row).
        const int half = lane >> 5;
        const int l32  = lane & 31;
        unsigned long long hits = ~ovf;             // all 64 lanes are valid
        #pragma unroll 1
        while (hits) {                              // wave-uniform mask
            int j0 = __ffsll(hits) - 1;
            hits &= hits - 1;
            const bool dup = (hits == 0);           // odd count: duplicate j0
            int j1 = dup ? j0 : (__ffsll(hits) - 1);
            if (!dup) hits &= hits - 1;
            int r = __shfl(rem, half ? j1 : j0, 64);
            const float4* __restrict__ row =
                (const float4*)(emb + (size_t)r * EMB_DIM);
            float4 v = row[l32];
            float s4 = (v.x + v.y) + (v.z + v.w);
            accl += (half && dup) ? 0.0f : s4;      // drop the duplicated half
        }
    }

    // wave reduction (64 lanes)
    #pragma unroll
    for (int o = 32; o > 0; o >>= 1)
        accl += __shfl_down(accl, o, 64);

    __shared__ float wsum[BLOCK / 64];
    if (lane == 0) wsum[wave] = accl;
    __syncthreads();
    if (threadIdx.x == 0) {
        float s = 0.0f;
        #pragma unroll
        for (int w = 0; w < BLOCK / 64; ++w) s += wsum[w];
        partials[blockIdx.x] = s;
    }
}

__global__ __launch_bounds__(256) void finalize_kernel(
    const float* __restrict__ partials, float* __restrict__ out)
{
    __shared__ double sh[256];
    double s = 0.0;
    for (int i = threadIdx.x; i < GRID; i += 256)
        s += (double)partials[i];
    sh[threadIdx.x] = s;
    __syncthreads();
    #pragma unroll
    for (int stride = 128; stride > 0; stride >>= 1) {
        if (threadIdx.x < stride) sh[threadIdx.x] += sh[threadIdx.x + stride];
        __syncthreads();
    }
    if (threadIdx.x == 0)
        out[0] = (float)(sh[0] / ((double)TOTAL * (double)EMB_DIM));
}

extern "C" void kernel_launch(void* const* d_in, const int* in_sizes, int n_in,
                              void* d_out, int out_size, void* d_ws, size_t ws_size,
                              hipStream_t stream) {
    const int*   ids0 = (const int*)d_in[0];
    const int*   ids1 = (const int*)d_in[1];
    const int*   mch0 = (const int*)d_in[2];
    const int*   mch1 = (const int*)d_in[3];
    const float* emb0 = (const float*)d_in[4];
    const float* emb1 = (const float*)d_in[5];

    float* out      = (float*)d_out;
    float* partials = (float*)d_ws;

    remap_loss_kernel<<<GRID, BLOCK, 0, stream>>>(
        ids0, ids1, mch0, mch1, emb0, emb1, out, partials);
    finalize_kernel<<<1, 256, 0, stream>>>(partials, out);
}

// Round 5
// 380.786 us; speedup vs baseline: 1.2092x; 1.2092x over previous
//
#include <hip/hip_runtime.h>
#include <stdint.h>

#define N_IDS     1000000
#define ZCH       400000
#define EMB_DIM   128
#define TOTAL     (2 * N_IDS)
#define HASH_SZ   4000000            // id values are in [0, 4M)
#define BLOCK     256
#define GRID      ((TOTAL + BLOCK - 1) / BLOCK)   // 7813
#define OVF       (ZCH - 1)

// Round-5: revert to the measurement-proven R0 structure (int32 LUT,
// init+scatter+remap+finalize, 383 us) and software-pipeline the loss
// loop, order-preserving:
//   - issue the first row-pair load BEFORE the (L1-hot) OVF-row block
//   - issue pair k+1's load before consuming pair k  -> compiler waits
//     vmcnt(1) instead of vmcnt(0), hiding ~900cy cold-row latency
// Per-lane accl += sequence is IDENTICAL to R0 -> bit-exact loss.
//
// Session ledger: R2 fused-finalize __threadfence per block = +370 us
// (per-XCD L2 writeback storm). R4 per-thread binary search = latency-
// bound 152 us remap (19 dependent gathers). Both reverted.
//
// d_out (float32): [0] = loss, [1 .. 2M] = remapped indices as floats.
// d_ws layout: [lut0: 4M ints][lut1: 4M ints][partials: GRID floats]

__global__ __launch_bounds__(256) void init_lut_kernel(int4* __restrict__ lut)
{
    // 2 features x 4M ints = 8M ints = 2M int4 stores
    int t = blockIdx.x * blockDim.x + threadIdx.x;
    if (t < (2 * HASH_SZ) / 4)
        lut[t] = make_int4(OVF, OVF, OVF, OVF);
}

__global__ __launch_bounds__(256) void scatter_lut_kernel(
    const int* __restrict__ mch0, const int* __restrict__ mch1,
    int* __restrict__ lut0, int* __restrict__ lut1)
{
    int t = blockIdx.x * blockDim.x + threadIdx.x;
    if (t >= 2 * ZCH) return;
    const int feat = t >= ZCH;
    const int s    = feat ? (t - ZCH) : t;
    const int* __restrict__ mch = feat ? mch1 : mch0;
    int* __restrict__ lut       = feat ? lut1 : lut0;
    const int v = mch[s];
    // searchsorted-left: only the FIRST occurrence of a value owns the slot.
    if (s == 0 || mch[s - 1] != v)
        lut[v] = s;
}

__global__ __launch_bounds__(BLOCK) void remap_loss_kernel(
    const int* __restrict__ ids0, const int* __restrict__ ids1,
    const float* __restrict__ emb0, const float* __restrict__ emb1,
    const int* __restrict__ lut0, const int* __restrict__ lut1,
    float* __restrict__ out,
    float* __restrict__ partials)
{
    const int gid  = blockIdx.x * BLOCK + threadIdx.x;
    const int lane = threadIdx.x & 63;
    const int wave = threadIdx.x >> 6;

    float accl = 0.0f;

    // Wave-uniform activity/feature: TOTAL % 64 == 0 and N_IDS % 64 == 0.
    const bool active = (gid < TOTAL);
    if (active) {
        const int feat = gid >= N_IDS;
        const int i    = feat ? (gid - N_IDS) : gid;
        const int id   = (feat ? ids1 : ids0)[i];
        const float* __restrict__ emb = feat ? emb1 : emb0;

        const int rem = (feat ? lut1 : lut0)[id];   // the whole "search"

        out[1 + gid] = (float)rem;                  // exact: rem < 2^24

        const unsigned long long ovf = __ballot(rem == OVF);
        const int novf = __popcll(ovf);

        const int half = lane >> 5;
        const int l32  = lane & 31;
        unsigned long long hits = ~ovf;             // all 64 lanes valid

        // ---- pipeline prologue: issue first cold row-pair load NOW, so it
        // overlaps the L1-hot OVF-row processing below. Loads only; no FP
        // order change.
        float4 vcur; bool dup_cur = false; bool have = (hits != 0ull);
        if (have) {
            int j0 = __ffsll(hits) - 1; hits &= hits - 1;
            const bool dup = (hits == 0);
            int j1 = dup ? j0 : (__ffsll(hits) - 1);
            if (!dup) hits &= hits - 1;
            int r = __shfl(rem, half ? j1 : j0, 64);
            vcur = ((const float4*)(emb + (size_t)r * EMB_DIM))[l32];
            dup_cur = dup;
        }

        // ---- loss: ~90.5% of ids hit the overflow row: dedupe it (L1-hot).
        if (novf) {
            const float2* __restrict__ row =
                (const float2*)(emb + (size_t)OVF * EMB_DIM);
            float2 v = row[lane];                   // 64 x 8 B = one row
            float s = v.x + v.y;
            #pragma unroll
            for (int o = 32; o > 0; o >>= 1)
                s += __shfl_xor(s, o, 64);
            if (lane == 0) accl += (float)novf * s;
        }

        // ---- remaining ~6 distinct rows per wave: 2 rows/iteration,
        // half-wave x float4 (32 x 16 B = 512 B = one row), double-buffered:
        // next pair's load is in flight while the current pair is consumed.
        #pragma unroll 1
        while (have) {                              // wave-uniform
            float4 vnxt; bool dup_nxt = false;
            const bool have_nxt = (hits != 0ull);
            if (have_nxt) {
                int j0 = __ffsll(hits) - 1; hits &= hits - 1;
                const bool dup = (hits == 0);
                int j1 = dup ? j0 : (__ffsll(hits) - 1);
                if (!dup) hits &= hits - 1;
                int r = __shfl(rem, half ? j1 : j0, 64);
                vnxt = ((const float4*)(emb + (size_t)r * EMB_DIM))[l32];
                dup_nxt = dup;
            }
            // consume current pair (same arithmetic, same per-lane order as R0)
            float s4 = (vcur.x + vcur.y) + (vcur.z + vcur.w);
            accl += (half && dup_cur) ? 0.0f : s4;  // drop duplicated half
            vcur = vnxt; dup_cur = dup_nxt; have = have_nxt;
        }
    }

    // wave reduction (64 lanes)
    #pragma unroll
    for (int o = 32; o > 0; o >>= 1)
        accl += __shfl_down(accl, o, 64);

    __shared__ float wsum[BLOCK / 64];
    if (lane == 0) wsum[wave] = accl;
    __syncthreads();
    if (threadIdx.x == 0) {
        float s = 0.0f;
        #pragma unroll
        for (int w = 0; w < BLOCK / 64; ++w) s += wsum[w];
        partials[blockIdx.x] = s;
    }
}

__global__ __launch_bounds__(256) void finalize_kernel(
    const float* __restrict__ partials, float* __restrict__ out)
{
    __shared__ double sh[256];
    double s = 0.0;
    for (int i = threadIdx.x; i < GRID; i += 256)
        s += (double)partials[i];
    sh[threadIdx.x] = s;
    __syncthreads();
    #pragma unroll
    for (int stride = 128; stride > 0; stride >>= 1) {
        if (threadIdx.x < stride) sh[threadIdx.x] += sh[threadIdx.x + stride];
        __syncthreads();
    }
    if (threadIdx.x == 0)
        out[0] = (float)(sh[0] / ((double)TOTAL * (double)EMB_DIM));
}

extern "C" void kernel_launch(void* const* d_in, const int* in_sizes, int n_in,
                              void* d_out, int out_size, void* d_ws, size_t ws_size,
                              hipStream_t stream) {
    const int*   ids0 = (const int*)d_in[0];
    const int*   ids1 = (const int*)d_in[1];
    const int*   mch0 = (const int*)d_in[2];
    const int*   mch1 = (const int*)d_in[3];
    const float* emb0 = (const float*)d_in[4];
    const float* emb1 = (const float*)d_in[5];

    float* out      = (float*)d_out;
    int*   lut0     = (int*)d_ws;
    int*   lut1     = lut0 + HASH_SZ;
    float* partials = (float*)(lut1 + HASH_SZ);

    init_lut_kernel<<<((2 * HASH_SZ / 4) + 255) / 256, 256, 0, stream>>>(
        (int4*)d_ws);
    scatter_lut_kernel<<<(2 * ZCH + 255) / 256, 256, 0, stream>>>(
        mch0, mch1, lut0, lut1);
    remap_loss_kernel<<<GRID, BLOCK, 0, stream>>>(
        ids0, ids1, emb0, emb1, lut0, lut1, out, partials);
    finalize_kernel<<<1, 256, 0, stream>>>(partials, out);
}